// Round 3
// baseline (216.288 us; speedup 1.0000x reference)
//
#include <hip/hip_runtime.h>
#include <hip/hip_bf16.h>

// 12-qubit statevector pipeline, fp32.
// Split path: prep (gate tables) -> enc64 (1-wave blocks, 64 amps/thread)
//             -> proj64 (1-wave blocks) -> qhead. Mono fallback if ws small.

// ---------------- ws layout (floats) ----------------
#define N_STATE_F (512 * 8192)            // 4,194,304 : encoded states (re|im planes)
#define WS_FEAT   N_STATE_F               // K 12288 | V 12288 | Q 192
#define WS_PTAB   (WS_FEAT + 24768)       // 144 gates * float4 = 576 floats
#define WS_UTAB   (WS_PTAB + 576)         // 36 gates * 8 floats = 288
#define WS_TOTAL  (WS_UTAB + 288)

#define SWZ(j) ((j) ^ (((j) >> 6) & 63))

__device__ __forceinline__ float xorf(float a, unsigned m) {
  return __int_as_float(__float_as_int(a) ^ (int)m);
}

// read maps: 1 = encode ladder+ring, 2 = CX_LONG, 3 = ladder only
template <int MODE>
__device__ __forceinline__ int mapIdxT(int j) {
  if constexpr (MODE == 1) { int k = j ^ ((j >> 11) & 1); return k ^ ((k & 0x7FF) << 1); }
  else if constexpr (MODE == 2) return j ^ ((j & 1) << 11);
  else if constexpr (MODE == 3) return j ^ ((j & 0x7FF) << 1);
  else return j;
}

// ---------- 64-amp register-tile helpers (1 wave = 64 lanes) ----------
// Layout A: j = (lane<<6)|r  (qubits 0-5 register-local)
// Layout B: j = (r<<6)|lane  (qubits 6-11 register-local)

__device__ __forceinline__ void wA64(float* sR, float* sI, int l,
                                     const float (&ar)[64], const float (&ai)[64]) {
#pragma unroll
  for (int r = 0; r < 64; ++r) {
    int idx = SWZ((l << 6) | r);
    sR[idx] = ar[r]; sI[idx] = ai[r];
  }
}
__device__ __forceinline__ void wB64(float* sR, float* sI, int l,
                                     const float (&ar)[64], const float (&ai)[64]) {
#pragma unroll
  for (int r = 0; r < 64; ++r) {
    int idx = SWZ((r << 6) | l);
    sR[idx] = ar[r]; sI[idx] = ai[r];
  }
}
template <int MODE>
__device__ __forceinline__ void rA64(const float* sR, const float* sI, int l,
                                     float (&ar)[64], float (&ai)[64]) {
#pragma unroll
  for (int r = 0; r < 64; ++r) {
    int idx = SWZ(mapIdxT<MODE>((l << 6) | r));
    ar[r] = sR[idx]; ai[r] = sI[idx];
  }
}
template <int MODE>
__device__ __forceinline__ void rB64(const float* sR, const float* sI, int l,
                                     float (&ar)[64], float (&ai)[64]) {
#pragma unroll
  for (int r = 0; r < 64; ++r) {
    int idx = SWZ(mapIdxT<MODE>((r << 6) | l));
    ar[r] = sR[idx]; ai[r] = sI[idx];
  }
}

// U3 gate on register bit B; u = {ct,0,u01r,u01i,u10r,u10i,u11r,u11i} (u00 real)
template <int B>
__device__ __forceinline__ void u3g(float (&ar)[64], float (&ai)[64], const float* u) {
  float u00 = u[0], u01r = u[2], u01i = u[3], u10r = u[4], u10i = u[5], u11r = u[6], u11i = u[7];
#pragma unroll
  for (int m = 0; m < 32; ++m) {
    int p0 = ((m >> B) << (B + 1)) | (m & ((1 << B) - 1));
    int p1 = p0 | (1 << B);
    float x0r = ar[p0], x0i = ai[p0], x1r = ar[p1], x1i = ai[p1];
    ar[p0] = u00 * x0r + u01r * x1r - u01i * x1i;
    ai[p0] = u00 * x0i + u01r * x1i + u01i * x1r;
    ar[p1] = u10r * x0r - u10i * x0i + u11r * x1r - u11i * x1i;
    ai[p1] = u10r * x0i + u10i * x0r + u11r * x1i + u11i * x1r;
  }
}
__device__ __forceinline__ void u3Group6(float (&ar)[64], float (&ai)[64], const float* ub) {
  u3g<0>(ar, ai, ub);       u3g<1>(ar, ai, ub + 8);   u3g<2>(ar, ai, ub + 16);
  u3g<3>(ar, ai, ub + 24);  u3g<4>(ar, ai, ub + 32);  u3g<5>(ar, ai, ub + 40);
}

// Fused RY+RZ (global phase dropped): G = diag(1, e^{i phi}) * RY(theta)
template <int B>
__device__ __forceinline__ void ryrzg(float (&ar)[64], float (&ai)[64], float4 g) {
  float c = g.x, s = g.y, zr = g.z, zi = g.w;
#pragma unroll
  for (int m = 0; m < 32; ++m) {
    int p0 = ((m >> B) << (B + 1)) | (m & ((1 << B) - 1));
    int p1 = p0 | (1 << B);
    float x0r = ar[p0], x0i = ai[p0], x1r = ar[p1], x1i = ai[p1];
    float n0r = c * x0r - s * x1r;
    float n0i = c * x0i - s * x1i;
    float wr  = s * x0r + c * x1r;
    float wi  = s * x0i + c * x1i;
    ar[p0] = n0r;               ai[p0] = n0i;
    ar[p1] = wr * zr - wi * zi; ai[p1] = wr * zi + wi * zr;
  }
}
__device__ __forceinline__ void ryrzGroup6(float (&ar)[64], float (&ai)[64], const float4* gt) {
  ryrzg<0>(ar, ai, gt[0]); ryrzg<1>(ar, ai, gt[1]); ryrzg<2>(ar, ai, gt[2]);
  ryrzg<3>(ar, ai, gt[3]); ryrzg<4>(ar, ai, gt[4]); ryrzg<5>(ar, ai, gt[5]);
}

// CZ phase in layout B. TYPE 0: mask 0x555 (pairs split lane/reg cleanly)
// TYPE 1: mask 0x2AA (cross pair (5,6) = lane5 & reg0)
template <int TYPE>
__device__ __forceinline__ void czB64(float (&ar)[64], float (&ai)[64], int l) {
  if constexpr (TYPE == 0) {
    unsigned mL = (unsigned)(__popc((l & (l >> 1)) & 0x15) & 1) << 31;
#pragma unroll
    for (int r = 0; r < 64; ++r) {
      unsigned m = mL ^ ((unsigned)(__popc((r & (r >> 1)) & 0x15) & 1) << 31);
      ar[r] = xorf(ar[r], m); ai[r] = xorf(ai[r], m);
    }
  } else {
    unsigned mE = (unsigned)(__popc((l & (l >> 1)) & 0xA) & 1) << 31;
    unsigned mO = mE ^ ((unsigned)((l >> 5) & 1) << 31);
#pragma unroll
    for (int r = 0; r < 64; ++r) {
      unsigned m = ((r & 1) ? mO : mE) ^ ((unsigned)(__popc((r & (r >> 1)) & 0xA) & 1) << 31);
      ar[r] = xorf(ar[r], m); ai[r] = xorf(ai[r], m);
    }
  }
}

// ---------------- prep: gate tables -> ws ----------------
__global__ void prep_kernel(const float* __restrict__ hparams,
                            const float* __restrict__ resp, float* __restrict__ ws) {
  int t = threadIdx.x;
  float4* ptab = (float4*)(ws + WS_PTAB);
  for (int idx = t; idx < 144; idx += 256) {
    int pj = idx / 24, k = idx % 24;
    const float* hp = hparams + pj * 48;
    float s, c;  sincosf(0.5f * hp[2 * k], &s, &c);
    float zi, zr; sincosf(hp[2 * k + 1], &zi, &zr);
    ptab[idx] = make_float4(c, s, zr, zi);
  }
  if (t < 36) {
    const float* rp = resp + t * 3;
    float st, ct;  sincosf(0.5f * rp[0], &st, &ct);
    float sp2, cp; sincosf(rp[1], &sp2, &cp);
    float sl, cl;  sincosf(rp[2], &sl, &cl);
    float spl, cpl; sincosf(rp[1] + rp[2], &spl, &cpl);
    float* u = ws + WS_UTAB + t * 8;
    u[0] = ct;       u[1] = 0.0f;
    u[2] = -cl * st; u[3] = -sl * st;
    u[4] = cp * st;  u[5] = sp2 * st;
    u[6] = cpl * ct; u[7] = spl * ct;
  }
}

// ---------------- enc64: one wave per state ----------------
__global__ __launch_bounds__(64) void enc64_kernel(
    const float* __restrict__ seq, const float* __restrict__ utabG,
    float* __restrict__ wsStates) {
  __shared__ float sRe[4096], sIm[4096];
  __shared__ float4 qtab[12];
  const int l = threadIdx.x;
  const int s = blockIdx.x;
  const float x = seq[s];
  const float PI = 3.14159265358979323846f;
  const float RS2 = 0.70710678118654752440f;
  if (l < 12) {
    float th = x * PI * (float)(l + 1) / 12.0f;
    float ph = x * PI / (float)(l + 1);
    float sn, cs;  sincosf(0.5f * th, &sn, &cs);
    float zi, zr;  sincosf(0.5f * ph, &zi, &zr);
    float k0 = (cs - sn) * RS2, k1 = (cs + sn) * RS2;
    qtab[l] = make_float4(k0 * zr, -k0 * zi, k1 * zr, k1 * zi);
  }
  __syncthreads();

  // product state in layout B regs (lane = qubits 0-5, reg = qubits 6-11)
  float ar[64], ai[64];
  float pr, pi;
  { float4 g = qtab[0]; pr = (l & 1) ? g.z : g.x; pi = (l & 1) ? g.w : g.y; }
#pragma unroll
  for (int q = 1; q < 6; ++q) {
    float4 g = qtab[q];
    int bb = (l >> q) & 1;
    float fr = bb ? g.z : g.x, fi = bb ? g.w : g.y;
    float nr = pr * fr - pi * fi; pi = pr * fi + pi * fr; pr = nr;
  }
  ar[0] = pr; ai[0] = pi;
#pragma unroll
  for (int k = 0; k < 6; ++k) {
    float4 g = qtab[6 + k];
#pragma unroll
    for (int m = 0; m < (1 << k); ++m) {
      float xr = ar[m], xi = ai[m];
      ar[m | (1 << k)] = xr * g.z - xi * g.w;
      ai[m | (1 << k)] = xr * g.w + xi * g.z;
      ar[m] = xr * g.x - xi * g.y;
      ai[m] = xr * g.y + xi * g.x;
    }
  }

  wB64(sRe, sIm, l, ar, ai); __syncthreads();
  rA64<1>(sRe, sIm, l, ar, ai);                 // init ladder+ring fold
  u3Group6(ar, ai, utabG + 0);                  // layer1 qubits 0-5
  __syncthreads(); wA64(sRe, sIm, l, ar, ai); __syncthreads();
  rB64<0>(sRe, sIm, l, ar, ai);
  u3Group6(ar, ai, utabG + 6 * 8);              // layer1 qubits 6-11
  czB64<0>(ar, ai, l);                          // CZ 0x555
  __syncthreads(); wB64(sRe, sIm, l, ar, ai); __syncthreads();
  rA64<2>(sRe, sIm, l, ar, ai);                 // CX_LONG fold
  u3Group6(ar, ai, utabG + 12 * 8);             // layer2 qubits 0-5
  __syncthreads(); wA64(sRe, sIm, l, ar, ai); __syncthreads();
  rB64<0>(sRe, sIm, l, ar, ai);
  u3Group6(ar, ai, utabG + 18 * 8);             // layer2 qubits 6-11
  czB64<1>(ar, ai, l);                          // CZ 0x2AA
  __syncthreads(); wB64(sRe, sIm, l, ar, ai); __syncthreads();
  rA64<2>(sRe, sIm, l, ar, ai);                 // CX_LONG fold
  u3Group6(ar, ai, utabG + 24 * 8);             // layer3 qubits 0-5
  __syncthreads(); wA64(sRe, sIm, l, ar, ai); __syncthreads();
  rB64<0>(sRe, sIm, l, ar, ai);
  u3Group6(ar, ai, utabG + 30 * 8);             // layer3 qubits 6-11
  czB64<0>(ar, ai, l);                          // CZ 0x555

  // store with trailing CX_LONG folded: g = j ^ ((j&1)<<11), j=(r<<6)|l
  float* gR = wsStates + (size_t)s * 8192;
  float* gI = gR + 4096;
  int lf5 = (l & 1) << 5;
#pragma unroll
  for (int r = 0; r < 64; ++r) {
    int g = ((r ^ lf5) << 6) | l;
    gR[g] = ar[r]; gI[g] = ai[r];
  }
}

// ---------------- proj64: one wave per projection ----------------
__global__ __launch_bounds__(64) void proj64_kernel(
    const float* __restrict__ wsStates, const float* __restrict__ ptabG,
    float* __restrict__ featBase) {
  __shared__ float sRe[4096], sIm[4096];
  const int l = threadIdx.x;
  const int bid = blockIdx.x;
  int h, which, s;
  if (bid < 2048) { s = bid >> 2; int pp = bid & 3; h = pp >> 1; which = 1 + (pp & 1); }
  else            { int i = bid - 2048; h = i & 1; s = (((i >> 1) << 6) | 63); which = 0; }
  const int b = s >> 6, t = s & 63;
  const float4* gt = (const float4*)ptabG + (h * 3 + which) * 24;
  const float* stR = wsStates + (size_t)s * 8192;
  const float* stI = stR + 4096;

  float ar[64], ai[64];
#pragma unroll
  for (int r = 0; r < 64; ++r) {          // layout B load: coalesced
    ar[r] = stR[(r << 6) | l];
    ai[r] = stI[(r << 6) | l];
  }
  // layer0 (gates commute within a layer): qubits 6-11 first
  ryrzGroup6(ar, ai, gt + 6);
  __syncthreads(); wB64(sRe, sIm, l, ar, ai); __syncthreads();
  rA64<0>(sRe, sIm, l, ar, ai);
  ryrzGroup6(ar, ai, gt + 0);             // qubits 0-5
  __syncthreads(); wA64(sRe, sIm, l, ar, ai); __syncthreads();
  rB64<3>(sRe, sIm, l, ar, ai);           // inter-layer ladder fold
  ryrzGroup6(ar, ai, gt + 18);            // layer1 qubits 6-11
  __syncthreads(); wB64(sRe, sIm, l, ar, ai); __syncthreads();
  rA64<0>(sRe, sIm, l, ar, ai);
  ryrzGroup6(ar, ai, gt + 12);            // layer1 qubits 0-5

  // features in layout A (lane = j bits 6-11, reg = j bits 0-5);
  // sign_q(j) = parity(j bits 0..11-q), final ladder folded via prefix parity
  float acc0 = 0, a7 = 0, a8 = 0, a9 = 0, a10 = 0, a11 = 0;
#pragma unroll
  for (int r = 0; r < 64; ++r) {
    float p = ar[r] * ar[r] + ai[r] * ai[r];
    if (__popc(r & 63) & 1) acc0 -= p; else acc0 += p;
    if (__popc(r & 31) & 1) a7 -= p; else a7 += p;
    if (__popc(r & 15) & 1) a8 -= p; else a8 += p;
    if (__popc(r & 7) & 1)  a9 -= p; else a9 += p;
    if (__popc(r & 3) & 1)  a10 -= p; else a10 += p;
    if (__popc(r & 1) & 1)  a11 -= p; else a11 += p;
  }
  float f[12];
  f[0] = xorf(acc0, (unsigned)(__popc(l & 63) & 1) << 31);
  f[1] = xorf(acc0, (unsigned)(__popc(l & 31) & 1) << 31);
  f[2] = xorf(acc0, (unsigned)(__popc(l & 15) & 1) << 31);
  f[3] = xorf(acc0, (unsigned)(__popc(l & 7) & 1) << 31);
  f[4] = xorf(acc0, (unsigned)(__popc(l & 3) & 1) << 31);
  f[5] = xorf(acc0, (unsigned)(__popc(l & 1) & 1) << 31);
  f[6] = acc0; f[7] = a7; f[8] = a8; f[9] = a9; f[10] = a10; f[11] = a11;
#pragma unroll
  for (int q = 0; q < 12; ++q) {
#pragma unroll
    for (int off = 32; off; off >>= 1) f[q] += __shfl_xor(f[q], off, 64);
  }
  if (l == 0) {
    float* dst;
    if (which == 1)      dst = featBase + (((h << 3) + b) * 64 + t) * 12;
    else if (which == 2) dst = featBase + 12288 + (((h << 3) + b) * 64 + t) * 12;
    else                 dst = featBase + 24576 + ((h << 3) + b) * 12;
#pragma unroll
    for (int q = 0; q < 12; ++q) dst[q] = f[q];
  }
}

// ================= MONO FALLBACK (validated R1 structure) =================
#define PADDED 4224
__device__ __forceinline__ int PD(int j) { return j + (j >> 5); }
__device__ __forceinline__ int mapIdx(int j, int mode) {
  if (mode == 1) { int k = j ^ ((j >> 11) & 1); return k ^ ((k & 0x7FF) << 1); }
  if (mode == 2) { return j ^ ((j & 1) << 11); }
  if (mode == 3) { return j ^ ((j & 0x7FF) << 1); }
  return j;
}
template <int L>
__device__ __forceinline__ int layoutIdx(int tid, int r) {
  if constexpr (L == 0) return (tid << 4) | r;
  else if constexpr (L == 1) return ((tid & 0xF0) << 4) | (r << 4) | (tid & 15);
  else return (r << 8) | tid;
}
template <int L>
__device__ __forceinline__ void ldsRead16(const float* sR, const float* sI, int tid, int mode,
                                          float ar[16], float ai[16]) {
#pragma unroll
  for (int r = 0; r < 16; ++r) {
    int a = PD(mapIdx(layoutIdx<L>(tid, r), mode));
    ar[r] = sR[a]; ai[r] = sI[a];
  }
}
template <int L>
__device__ __forceinline__ void ldsWrite16(float* sR, float* sI, int tid,
                                           const float ar[16], const float ai[16], int czmask) {
#pragma unroll
  for (int r = 0; r < 16; ++r) {
    int j = layoutIdx<L>(tid, r);
    float vr = ar[r], vi = ai[r];
    if (czmask) {
      float sg = (__popc((j & (j >> 1)) & czmask) & 1) ? -1.0f : 1.0f;
      vr *= sg; vi *= sg;
    }
    int a = PD(j);
    sR[a] = vr; sI[a] = vi;
  }
}
__device__ __forceinline__ void applyU34(float ar[16], float ai[16], const float (*ut)[8]) {
#pragma unroll
  for (int b = 0; b < 4; ++b) {
    const float* u = ut[b];
    float u00r = u[0], u01r = u[2], u01i = u[3];
    float u10r = u[4], u10i = u[5], u11r = u[6], u11i = u[7];
#pragma unroll
    for (int m = 0; m < 8; ++m) {
      int p0 = ((m >> b) << (b + 1)) | (m & ((1 << b) - 1));
      int p1 = p0 | (1 << b);
      float x0r = ar[p0], x0i = ai[p0], x1r = ar[p1], x1i = ai[p1];
      ar[p0] = u00r * x0r + u01r * x1r - u01i * x1i;
      ai[p0] = u00r * x0i + u01r * x1i + u01i * x1r;
      ar[p1] = u10r * x0r - u10i * x0i + u11r * x1r - u11i * x1i;
      ai[p1] = u10r * x0i + u10i * x0r + u11r * x1i + u11i * x1r;
    }
  }
}
__device__ __forceinline__ void applyRyRz4(float ar[16], float ai[16], const float4* gt) {
#pragma unroll
  for (int b = 0; b < 4; ++b) {
    float4 g = gt[b];
    float c = g.x, s = g.y, zr = g.z, zi = g.w;
#pragma unroll
    for (int m = 0; m < 8; ++m) {
      int p0 = ((m >> b) << (b + 1)) | (m & ((1 << b) - 1));
      int p1 = p0 | (1 << b);
      float x0r = ar[p0], x0i = ai[p0], x1r = ar[p1], x1i = ai[p1];
      float n0r = c * x0r - s * x1r;
      float n0i = c * x0i - s * x1i;
      float wr  = s * x0r + c * x1r;
      float wi  = s * x0i + c * x1i;
      ar[p0] = n0r;               ai[p0] = n0i;
      ar[p1] = wr * zr - wi * zi; ai[p1] = wr * zi + wi * zr;
    }
  }
}
template <int L>
__device__ __forceinline__ void encPass(float* sR, float* sI, int tid, int mode,
                                        const float (*ut)[8], int czmask) {
  float ar[16], ai[16];
  ldsRead16<L>(sR, sI, tid, mode, ar, ai);
  if (mode != 0) __syncthreads();
  applyU34(ar, ai, ut);
  ldsWrite16<L>(sR, sI, tid, ar, ai, czmask);
  __syncthreads();
}
template <int L>
__device__ __forceinline__ void projPass(float* sR, float* sI, int tid, int mode, const float4* gt) {
  float ar[16], ai[16];
  ldsRead16<L>(sR, sI, tid, mode, ar, ai);
  if (mode != 0) __syncthreads();
  applyRyRz4(ar, ai, gt);
  ldsWrite16<L>(sR, sI, tid, ar, ai, 0);
  __syncthreads();
}
__device__ __forceinline__ void projFinal(const float* sR, const float* sI, int tid,
                                          const float4* gt, float feat[12]) {
  float ar[16], ai[16];
#pragma unroll
  for (int r = 0; r < 16; ++r) {
    int a = PD((r << 8) | tid);
    ar[r] = sR[a]; ai[r] = sI[a];
  }
  applyRyRz4(ar, ai, gt);
  float sp = 0.f, f0 = 0.f, f1 = 0.f, f2 = 0.f, f3 = 0.f;
  int pt = __popc(tid) & 1;
#pragma unroll
  for (int r = 0; r < 16; ++r) {
    float p = ar[r] * ar[r] + ai[r] * ai[r];
    sp += p;
    int tr = r ^ (r << 1); tr ^= (tr << 2);
    f0 += ((pt ^ ((tr >> 3) & 1)) ? -p : p);
    f1 += ((pt ^ ((tr >> 2) & 1)) ? -p : p);
    f2 += ((pt ^ ((tr >> 1) & 1)) ? -p : p);
    f3 += ((pt ^ (tr & 1)) ? -p : p);
  }
  feat[0] = f0; feat[1] = f1; feat[2] = f2; feat[3] = f3;
  int tt = tid ^ (tid << 1); tt ^= (tt << 2); tt ^= (tt << 4);
#pragma unroll
  for (int q = 4; q < 12; ++q)
    feat[q] = ((tt >> (11 - q)) & 1) ? -sp : sp;
}
__device__ __forceinline__ float waveReduce(float v) {
#pragma unroll
  for (int off = 32; off; off >>= 1) v += __shfl_xor(v, off, 64);
  return v;
}
__device__ __forceinline__ void buildQtab(float4* qtab, int tid, float x) {
  const float PI = 3.14159265358979323846f;
  const float RS2 = 0.70710678118654752440f;
  if (tid < 12) {
    float th = x * PI * (float)(tid + 1) / 12.0f;
    float ph = x * PI / (float)(tid + 1);
    float s, c;  sincosf(0.5f * th, &s, &c);
    float zi, zr; sincosf(0.5f * ph, &zi, &zr);
    float k0 = (c - s) * RS2, k1 = (c + s) * RS2;
    qtab[tid] = make_float4(k0 * zr, -k0 * zi, k1 * zr, k1 * zi);
  }
}
__device__ __forceinline__ void buildUtab(float (*utab)[8], int tid, const float* resp) {
  if (tid >= 64 && tid < 100) {
    int i = tid - 64;
    const float* rp = resp + i * 3;
    float st, ct;  sincosf(0.5f * rp[0], &st, &ct);
    float sp2, cp; sincosf(rp[1], &sp2, &cp);
    float sl, cl;  sincosf(rp[2], &sl, &cl);
    float spl, cpl; sincosf(rp[1] + rp[2], &spl, &cpl);
    float* u = utab[i];
    u[0] = ct;       u[1] = 0.0f;
    u[2] = -cl * st; u[3] = -sl * st;
    u[4] = cp * st;  u[5] = sp2 * st;
    u[6] = cpl * ct; u[7] = spl * ct;
  }
}
__device__ __forceinline__ void initProduct(float* sRe, float* sIm, int tid, const float4* qtab) {
  float pr, pi;
  { float4 g = qtab[4]; int sb = tid & 1; pr = sb ? g.z : g.x; pi = sb ? g.w : g.y; }
#pragma unroll
  for (int q = 5; q < 12; ++q) {
    float4 g = qtab[q];
    int sb = (tid >> (q - 4)) & 1;
    float fr = sb ? g.z : g.x, fi = sb ? g.w : g.y;
    float nr = pr * fr - pi * fi;
    pi = pr * fi + pi * fr; pr = nr;
  }
  float4 g0 = qtab[0], g1 = qtab[1], g2 = qtab[2], g3 = qtab[3];
  float c01r[4], c01i[4], c23r[4], c23i[4];
#pragma unroll
  for (int i2 = 0; i2 < 4; ++i2) {
    float f0r = (i2 & 1) ? g0.z : g0.x, f0i = (i2 & 1) ? g0.w : g0.y;
    float f1r = (i2 & 2) ? g1.z : g1.x, f1i = (i2 & 2) ? g1.w : g1.y;
    c01r[i2] = f0r * f1r - f0i * f1i; c01i[i2] = f0r * f1i + f0i * f1r;
    float f2r = (i2 & 1) ? g2.z : g2.x, f2i = (i2 & 1) ? g2.w : g2.y;
    float f3r = (i2 & 2) ? g3.z : g3.x, f3i = (i2 & 2) ? g3.w : g3.y;
    c23r[i2] = f2r * f3r - f2i * f3i; c23i[i2] = f2r * f3i + f2i * f3r;
  }
#pragma unroll
  for (int r = 0; r < 16; ++r) {
    float lr = c01r[r & 3] * c23r[r >> 2] - c01i[r & 3] * c23i[r >> 2];
    float li = c01r[r & 3] * c23i[r >> 2] + c01i[r & 3] * c23r[r >> 2];
    int a = PD((tid << 4) | r);
    sRe[a] = pr * lr - pi * li;
    sIm[a] = pr * li + pi * lr;
  }
}
__device__ __forceinline__ void buildPtab(float4* ptab, int tid, const float* hp) {
  if (tid < 24) {
    int k = tid * 2;
    float s, c;  sincosf(0.5f * hp[k], &s, &c);
    float zi, zr; sincosf(hp[k + 1], &zi, &zr);
    ptab[tid] = make_float4(c, s, zr, zi);
  }
}
__global__ __launch_bounds__(256, 2) void qstates_mono(
    const float* __restrict__ seq, const float* __restrict__ resp,
    const float* __restrict__ hparams, float* __restrict__ featBase) {
  __shared__ float sRe[PADDED], sIm[PADDED];
  __shared__ float4 qtab[12];
  __shared__ float utab[36][8];
  __shared__ float4 ptab[24];
  __shared__ float red[4][12];
  const int tid = threadIdx.x;
  const int blk = blockIdx.x;
  const int b = blk >> 6, t = blk & 63;
  const float x = seq[blk];
  buildQtab(qtab, tid, x);
  buildUtab(utab, tid, resp);
  __syncthreads();
  initProduct(sRe, sIm, tid, qtab);
  __syncthreads();
  for (int l = 0; l < 3; ++l) {
    int czm = (l & 1) ? 0x2AA : 0x555;
    encPass<0>(sRe, sIm, tid, (l == 0) ? 1 : 2, &utab[l * 12], 0);
    encPass<1>(sRe, sIm, tid, 0, &utab[l * 12 + 4], 0);
    encPass<2>(sRe, sIm, tid, 0, &utab[l * 12 + 8], czm);
  }
  float encR[16], encI[16];
#pragma unroll
  for (int r = 0; r < 16; ++r) {
    int j = (tid << 4) | r;
    int a = PD(j ^ ((j & 1) << 11));
    encR[r] = sRe[a]; encI[r] = sIm[a];
  }
  const int nproj = (t == 63) ? 6 : 4;
  for (int pj = 0; pj < nproj; ++pj) {
    int h, which;
    if (pj < 4) { h = pj >> 1; which = (pj & 1) ? 2 : 1; }
    else        { h = pj - 4;  which = 0; }
    buildPtab(ptab, tid, hparams + (h * 3 + which) * 48);
    __syncthreads();
    float ar[16], ai[16];
#pragma unroll
    for (int r = 0; r < 16; ++r) { ar[r] = encR[r]; ai[r] = encI[r]; }
    applyRyRz4(ar, ai, &ptab[0]);
    ldsWrite16<0>(sRe, sIm, tid, ar, ai, 0);
    __syncthreads();
    projPass<1>(sRe, sIm, tid, 0, &ptab[4]);
    projPass<2>(sRe, sIm, tid, 0, &ptab[8]);
    projPass<0>(sRe, sIm, tid, 3, &ptab[12]);
    projPass<1>(sRe, sIm, tid, 0, &ptab[16]);
    float feat[12];
    projFinal(sRe, sIm, tid, &ptab[20], feat);
#pragma unroll
    for (int q = 0; q < 12; ++q) feat[q] = waveReduce(feat[q]);
    int wid = tid >> 6;
    if ((tid & 63) == 0) {
#pragma unroll
      for (int q = 0; q < 12; ++q) red[wid][q] = feat[q];
    }
    __syncthreads();
    if (tid < 12) {
      float v = red[0][tid] + red[1][tid] + red[2][tid] + red[3][tid];
      float* dst;
      if (which == 1)      dst = featBase + (((h << 3) + b) * 64 + t) * 12;
      else if (which == 2) dst = featBase + 12288 + (((h << 3) + b) * 64 + t) * 12;
      else                 dst = featBase + 24576 + ((h << 3) + b) * 12;
      dst[tid] = v;
    }
    __syncthreads();
  }
}

// ================= HEAD =================
__global__ __launch_bounds__(64) void qhead_kernel(
    const float* __restrict__ featBase,
    const float* __restrict__ W1, const float* __restrict__ b1,
    const float* __restrict__ W2, const float* __restrict__ b2,
    float* __restrict__ out) {
  __shared__ float feats[24];
  __shared__ float hdn[48];
  const int b = blockIdx.x;
  const int lane = threadIdx.x;
  const float* Kf = featBase;
  const float* Vf = featBase + 12288;
  const float* Qf = featBase + 24576;
  for (int h = 0; h < 2; ++h) {
    const float* q  = Qf + ((h << 3) + b) * 12;
    const float* kr = Kf + ((((h << 3) + b) << 6) + lane) * 12;
    float dot = 0.f;
#pragma unroll
    for (int d = 0; d < 12; ++d) dot += q[d] * kr[d];
    dot *= 0.288675134594812882f;
    float mx = dot;
#pragma unroll
    for (int off = 32; off; off >>= 1) mx = fmaxf(mx, __shfl_xor(mx, off, 64));
    float e = expf(dot - mx);
    float se = e;
#pragma unroll
    for (int off = 32; off; off >>= 1) se += __shfl_xor(se, off, 64);
    float a = e / se;
    const float* vr = Vf + ((((h << 3) + b) << 6) + lane) * 12;
#pragma unroll
    for (int d = 0; d < 12; ++d) {
      float v = a * vr[d];
#pragma unroll
      for (int off = 32; off; off >>= 1) v += __shfl_xor(v, off, 64);
      if (lane == 0) feats[h * 12 + d] = v;
    }
  }
  __syncthreads();
  if (lane < 48) {
    float acc = b1[lane];
#pragma unroll
    for (int f = 0; f < 24; ++f) acc += feats[f] * W1[f * 48 + lane];
    hdn[lane] = 0.5f * acc * (1.0f + erff(acc * 0.70710678118654752440f));
  }
  __syncthreads();
  if (lane < 4) {
    float acc = b2[lane];
#pragma unroll
    for (int k = 0; k < 48; ++k) acc += hdn[k] * W2[k * 4 + lane];
    out[(b << 2) | lane] = acc;
  }
}

extern "C" void kernel_launch(void* const* d_in, const int* in_sizes, int n_in,
                              void* d_out, int out_size, void* d_ws, size_t ws_size,
                              hipStream_t stream) {
  const float* seq     = (const float*)d_in[0];
  const float* resp    = (const float*)d_in[1];
  const float* hparams = (const float*)d_in[2];
  const float* W1      = (const float*)d_in[3];
  const float* b1      = (const float*)d_in[4];
  const float* W2      = (const float*)d_in[5];
  const float* b2      = (const float*)d_in[6];
  float* out = (float*)d_out;
  float* ws  = (float*)d_ws;

  const size_t needSplit = (size_t)WS_TOTAL * sizeof(float);
  if (ws_size >= needSplit) {
    float* wsStates = ws;
    float* featBase = ws + WS_FEAT;
    float* ptabG    = ws + WS_PTAB;
    float* utabG    = ws + WS_UTAB;
    hipLaunchKernelGGL(prep_kernel, dim3(1), dim3(256), 0, stream, hparams, resp, ws);
    hipLaunchKernelGGL(enc64_kernel, dim3(512), dim3(64), 0, stream, seq, utabG, wsStates);
    hipLaunchKernelGGL(proj64_kernel, dim3(2064), dim3(64), 0, stream, wsStates, ptabG, featBase);
    hipLaunchKernelGGL(qhead_kernel, dim3(8), dim3(64), 0, stream, featBase, W1, b1, W2, b2, out);
  } else {
    hipLaunchKernelGGL(qstates_mono, dim3(512), dim3(256), 0, stream, seq, resp, hparams, ws);
    hipLaunchKernelGGL(qhead_kernel, dim3(8), dim3(64), 0, stream, ws, W1, b1, W2, b2, out);
  }
}